// Round 2
// baseline (425.383 us; speedup 1.0000x reference)
//
#include <hip/hip_runtime.h>

#define IN_F   8192
#define OUT_F  14336
#define M_TOK  64
#define KP     (IN_F / 2)        // packed int32 per weight row = 4096
#define BN     64                // N-tile per block (4 waves x 16)
#define KSPLIT 16
#define KCHUNK (IN_F / KSPLIT)   // 512
#define NBLK   (OUT_F / BN)      // 224

typedef __attribute__((ext_vector_type(8))) short bf16x8;   // 8 bf16 (4 VGPRs)
typedef __attribute__((ext_vector_type(4))) float f32x4;    // MFMA C/D frag

__device__ __forceinline__ unsigned short f2bf_rne(float f) {
    unsigned u = __builtin_bit_cast(unsigned, f);
    u += 0x7FFFu + ((u >> 16) & 1u);
    return (unsigned short)(u >> 16);
}

// Prep: x fp32 -> bf16 into workspace, and out[m][n] = bias[n] (d_out is poisoned).
__global__ __launch_bounds__(256) void qlin_prep(const float* __restrict__ x,
                                                 const float* __restrict__ bias,
                                                 unsigned short* __restrict__ xb,
                                                 float* __restrict__ out) {
    const int XV = (M_TOK * IN_F) / 4;    // 131072 float4 of x
    const int OV = (M_TOK * OUT_F) / 4;   // 229376 float4 of out
    int gid = blockIdx.x * 256 + threadIdx.x;
    if (gid < XV) {
        float4 v = reinterpret_cast<const float4*>(x)[gid];
        ushort4 o;
        o.x = f2bf_rne(v.x);
        o.y = f2bf_rne(v.y);
        o.z = f2bf_rne(v.z);
        o.w = f2bf_rne(v.w);
        reinterpret_cast<ushort4*>(xb)[gid] = o;
    } else {
        int og = gid - XV;
        if (og < OV) {
            float4 b = reinterpret_cast<const float4*>(bias)[og % (OUT_F / 4)];
            reinterpret_cast<float4*>(out)[og] = b;
        }
    }
}

// Unpack one packed int32 (one byte: lo nibble = even k, hi nibble = odd k)
// into two bf16 bit-patterns packed in one dword. Ints in [-8,7] are exact in bf16.
__device__ __forceinline__ int unpack2_bf16(int v) {
    int q0 = ((int)((unsigned)v << 28)) >> 28;   // even k
    int q1 = ((int)((unsigned)v << 24)) >> 28;   // odd  k
    float f0 = (float)q0;
    float f1 = (float)q1;
    unsigned u0 = __builtin_bit_cast(unsigned, f0);
    unsigned u1 = __builtin_bit_cast(unsigned, f1);
    return (int)((u0 >> 16) | (u1 & 0xFFFF0000u));
}

// GEMM: each wave computes 64(M) x 16(N); block = 4 waves = 64 N. K split 16-way
// (3584 blocks = 14 blocks/CU of work, 8 resident -> 32 waves/CU), partials
// combined via fp32 atomicAdd into bias-initialized out (atomics resolve in L2).
__global__ __launch_bounds__(256, 8) void qlin_gemm(const unsigned short* __restrict__ xb,
                                                    const int* __restrict__ wp,
                                                    const float* __restrict__ scales,
                                                    float* __restrict__ out) {
    const int wave = threadIdx.x >> 6;
    const int lane = threadIdx.x & 63;
    const int t = lane & 15;     // A: m-within-tile ; B: n ; C/D: col (n)
    const int q = lane >> 4;     // A/B: k = q*8+j    ; C/D: row base q*4

    const int nblk = blockIdx.x % NBLK;
    const int kblk = blockIdx.x / NBLK;

    const int n  = nblk * BN + wave * 16 + t;     // weight row / output col
    const int k0 = kblk * KCHUNK + q * 8;         // this lane's k base

    const int*            __restrict__ wptr = wp + n * KP + (k0 >> 1);
    const unsigned short* __restrict__ xptr = xb + t * IN_F + k0;

    f32x4 acc0 = {0.f, 0.f, 0.f, 0.f};
    f32x4 acc1 = acc0, acc2 = acc0, acc3 = acc0;

#pragma unroll 4
    for (int kk = 0; kk < KCHUNK; kk += 32) {
        // B fragment: 8 consecutive weights of row n = 4 consecutive packed int32 (16 B)
        int4 wv = *reinterpret_cast<const int4*>(wptr + (kk >> 1));
        // A fragments: 8 consecutive bf16 of x rows (mt*16 + t), L2-hot
        bf16x8 a0 = *reinterpret_cast<const bf16x8*>(xptr + kk);
        bf16x8 a1 = *reinterpret_cast<const bf16x8*>(xptr + 16 * IN_F + kk);
        bf16x8 a2 = *reinterpret_cast<const bf16x8*>(xptr + 32 * IN_F + kk);
        bf16x8 a3 = *reinterpret_cast<const bf16x8*>(xptr + 48 * IN_F + kk);

        int4 pk;
        pk.x = unpack2_bf16(wv.x);
        pk.y = unpack2_bf16(wv.y);
        pk.z = unpack2_bf16(wv.z);
        pk.w = unpack2_bf16(wv.w);
        bf16x8 b = __builtin_bit_cast(bf16x8, pk);

        acc0 = __builtin_amdgcn_mfma_f32_16x16x32_bf16(a0, b, acc0, 0, 0, 0);
        acc1 = __builtin_amdgcn_mfma_f32_16x16x32_bf16(a1, b, acc1, 0, 0, 0);
        acc2 = __builtin_amdgcn_mfma_f32_16x16x32_bf16(a2, b, acc2, 0, 0, 0);
        acc3 = __builtin_amdgcn_mfma_f32_16x16x32_bf16(a3, b, acc3, 0, 0, 0);
    }

    const float sc = scales[n];
    const int mrow = q * 4;
#pragma unroll
    for (int r = 0; r < 4; ++r) {
        atomicAdd(&out[(     mrow + r) * OUT_F + n], acc0[r] * sc);
        atomicAdd(&out[(16 + mrow + r) * OUT_F + n], acc1[r] * sc);
        atomicAdd(&out[(32 + mrow + r) * OUT_F + n], acc2[r] * sc);
        atomicAdd(&out[(48 + mrow + r) * OUT_F + n], acc3[r] * sc);
    }
}

extern "C" void kernel_launch(void* const* d_in, const int* in_sizes, int n_in,
                              void* d_out, int out_size, void* d_ws, size_t ws_size,
                              hipStream_t stream) {
    const float* x     = (const float*)d_in[0];
    const int*   wp    = (const int*)d_in[1];
    const float* sc    = (const float*)d_in[2];
    const float* bias  = (const float*)d_in[3];
    float* out = (float*)d_out;
    unsigned short* xb = (unsigned short*)d_ws;   // 64*8192*2 = 1 MB

    const int prep_items = (M_TOK * IN_F) / 4 + (M_TOK * OUT_F) / 4;  // 360448
    qlin_prep<<<(prep_items + 255) / 256, 256, 0, stream>>>(x, bias, xb, out);
    qlin_gemm<<<NBLK * KSPLIT, 256, 0, stream>>>(xb, wp, sc, out);
}

// Round 3
// 408.173 us; speedup vs baseline: 1.0422x; 1.0422x over previous
//
#include <hip/hip_runtime.h>

#define IN_F   8192
#define OUT_F  14336
#define M_TOK  64
#define KP     (IN_F / 2)     // packed int32 per weight row = 4096
#define KW     (IN_F / 4)     // 2048 k per wave (4 waves split K within a block)
#define NB     16             // n per block
#define NBLK   (OUT_F / NB)   // 896 blocks
#define RSTR   68             // LDS reduce stride in floats (64 m + 4 pad, 16B-aligned)

typedef __attribute__((ext_vector_type(8))) short bf16x8;   // 8 bf16 (4 VGPRs)
typedef __attribute__((ext_vector_type(4))) float f32x4;    // MFMA C/D frag

__device__ __forceinline__ unsigned short f2bf_rne(float f) {
    unsigned u = __builtin_bit_cast(unsigned, f);
    u += 0x7FFFu + ((u >> 16) & 1u);
    return (unsigned short)(u >> 16);
}

// Prep: x fp32 -> bf16 workspace (out no longer needs bias-init; gemm writes it fully).
__global__ __launch_bounds__(256) void qlin_prep(const float* __restrict__ x,
                                                 unsigned short* __restrict__ xb) {
    int gid = blockIdx.x * 256 + threadIdx.x;   // 131072 float4 items
    float4 v = reinterpret_cast<const float4*>(x)[gid];
    ushort4 o;
    o.x = f2bf_rne(v.x);
    o.y = f2bf_rne(v.y);
    o.z = f2bf_rne(v.z);
    o.w = f2bf_rne(v.w);
    reinterpret_cast<ushort4*>(xb)[gid] = o;
}

// One packed int32 (one byte: lo nibble = even k, hi nibble = odd k) -> two bf16
// bit-patterns in one dword. Ints in [-8,7] are exact in bf16.
__device__ __forceinline__ int unpack2_bf16(int v) {
    int q0 = ((int)((unsigned)v << 28)) >> 28;
    int q1 = ((int)((unsigned)v << 24)) >> 28;
    unsigned u0 = __builtin_bit_cast(unsigned, (float)q0);
    unsigned u1 = __builtin_bit_cast(unsigned, (float)q1);
    return (int)((u0 >> 16) | (u1 & 0xFFFF0000u));
}

__device__ __forceinline__ bf16x8 unpack_b(int4 wv) {
    int4 pk;
    pk.x = unpack2_bf16(wv.x);
    pk.y = unpack2_bf16(wv.y);
    pk.z = unpack2_bf16(wv.z);
    pk.w = unpack2_bf16(wv.w);
    return __builtin_bit_cast(bf16x8, pk);
}

// Block = 16 n x 64 m x full K. Wave w handles k in [w*2048, (w+1)*2048): 64 iters.
// No atomics: LDS tree-reduce the 4 waves' accumulators, add bias, float4 store.
// __launch_bounds__(256,4): 128-VGPR budget so the explicit double-buffer keeps
// ~10 loads in flight per wave (ILP is the bet, not occupancy: grid = 896 blocks).
__global__ __launch_bounds__(256, 4) void qlin_gemm(const unsigned short* __restrict__ xb,
                                                    const int* __restrict__ wp,
                                                    const float* __restrict__ scales,
                                                    const float* __restrict__ bias,
                                                    float* __restrict__ out) {
    __shared__ float red[4 * NB * RSTR];   // L(w,n,m) = (w*16+n)*68 + m ; 17408 B

    const int wave = threadIdx.x >> 6;
    const int lane = threadIdx.x & 63;
    const int t = lane & 15;     // A: m ; B: n ; (both use lane&15)
    const int q = lane >> 4;     // A/B: k = q*8+j ; C/D: row base q*4

    const int n0 = blockIdx.x * NB;
    const int n  = n0 + t;                 // weight row / output col
    const int k0 = wave * KW + q * 8;      // this lane's k base

    const int*            __restrict__ wptr = wp + n * KP + (k0 >> 1);
    const unsigned short* __restrict__ xptr = xb + t * IN_F + k0;

    f32x4 acc0 = {0.f, 0.f, 0.f, 0.f};
    f32x4 acc1 = acc0, acc2 = acc0, acc3 = acc0;

    // ---- register double-buffered main loop: prefetch i+1 before MFMAs of i ----
    int4   wv = *reinterpret_cast<const int4*>(wptr);
    bf16x8 a0 = *reinterpret_cast<const bf16x8*>(xptr);
    bf16x8 a1 = *reinterpret_cast<const bf16x8*>(xptr + 16 * IN_F);
    bf16x8 a2 = *reinterpret_cast<const bf16x8*>(xptr + 32 * IN_F);
    bf16x8 a3 = *reinterpret_cast<const bf16x8*>(xptr + 48 * IN_F);

#pragma unroll 4
    for (int kk = 32; kk < KW; kk += 32) {
        int4   wvn = *reinterpret_cast<const int4*>(wptr + (kk >> 1));
        bf16x8 p0  = *reinterpret_cast<const bf16x8*>(xptr + kk);
        bf16x8 p1  = *reinterpret_cast<const bf16x8*>(xptr + 16 * IN_F + kk);
        bf16x8 p2  = *reinterpret_cast<const bf16x8*>(xptr + 32 * IN_F + kk);
        bf16x8 p3  = *reinterpret_cast<const bf16x8*>(xptr + 48 * IN_F + kk);

        bf16x8 b = unpack_b(wv);
        acc0 = __builtin_amdgcn_mfma_f32_16x16x32_bf16(a0, b, acc0, 0, 0, 0);
        acc1 = __builtin_amdgcn_mfma_f32_16x16x32_bf16(a1, b, acc1, 0, 0, 0);
        acc2 = __builtin_amdgcn_mfma_f32_16x16x32_bf16(a2, b, acc2, 0, 0, 0);
        acc3 = __builtin_amdgcn_mfma_f32_16x16x32_bf16(a3, b, acc3, 0, 0, 0);

        wv = wvn; a0 = p0; a1 = p1; a2 = p2; a3 = p3;
    }
    {   // last iteration
        bf16x8 b = unpack_b(wv);
        acc0 = __builtin_amdgcn_mfma_f32_16x16x32_bf16(a0, b, acc0, 0, 0, 0);
        acc1 = __builtin_amdgcn_mfma_f32_16x16x32_bf16(a1, b, acc1, 0, 0, 0);
        acc2 = __builtin_amdgcn_mfma_f32_16x16x32_bf16(a2, b, acc2, 0, 0, 0);
        acc3 = __builtin_amdgcn_mfma_f32_16x16x32_bf16(a3, b, acc3, 0, 0, 0);
    }

    // ---- scale by per-row (n) scale, park in LDS: red[(wave*16+n)*68 + m] ----
    const float sc = scales[n];
    acc0 *= sc; acc1 *= sc; acc2 *= sc; acc3 *= sc;

    float* rp = &red[(wave * NB + t) * RSTR + q * 4];
    *reinterpret_cast<f32x4*>(rp +  0) = acc0;   // m = q*4+r
    *reinterpret_cast<f32x4*>(rp + 16) = acc1;   // m = 16+q*4+r
    *reinterpret_cast<f32x4*>(rp + 32) = acc2;   // m = 32+q*4+r
    *reinterpret_cast<f32x4*>(rp + 48) = acc3;   // m = 48+q*4+r
    __syncthreads();

    // ---- reduce 4 waves, add bias, store: thread -> (m = tid>>2, 4 n's) ----
    const int m = threadIdx.x >> 2;
    const int c = threadIdx.x & 3;
    float4 bv = reinterpret_cast<const float4*>(bias + n0)[c];
    float4 ov;
    {
        const int nb = c * 4;
        ov.x = bv.x + red[(0*NB + nb+0)*RSTR + m] + red[(1*NB + nb+0)*RSTR + m]
                    + red[(2*NB + nb+0)*RSTR + m] + red[(3*NB + nb+0)*RSTR + m];
        ov.y = bv.y + red[(0*NB + nb+1)*RSTR + m] + red[(1*NB + nb+1)*RSTR + m]
                    + red[(2*NB + nb+1)*RSTR + m] + red[(3*NB + nb+1)*RSTR + m];
        ov.z = bv.z + red[(0*NB + nb+2)*RSTR + m] + red[(1*NB + nb+2)*RSTR + m]
                    + red[(2*NB + nb+2)*RSTR + m] + red[(3*NB + nb+2)*RSTR + m];
        ov.w = bv.w + red[(0*NB + nb+3)*RSTR + m] + red[(1*NB + nb+3)*RSTR + m]
                    + red[(2*NB + nb+3)*RSTR + m] + red[(3*NB + nb+3)*RSTR + m];
    }
    reinterpret_cast<float4*>(out + m * OUT_F + n0)[c] = ov;
}

extern "C" void kernel_launch(void* const* d_in, const int* in_sizes, int n_in,
                              void* d_out, int out_size, void* d_ws, size_t ws_size,
                              hipStream_t stream) {
    const float* x    = (const float*)d_in[0];
    const int*   wp   = (const int*)d_in[1];
    const float* sc   = (const float*)d_in[2];
    const float* bias = (const float*)d_in[3];
    float* out = (float*)d_out;
    unsigned short* xb = (unsigned short*)d_ws;   // 64*8192*2 = 1 MB

    qlin_prep<<<(M_TOK * IN_F) / 4 / 256, 256, 0, stream>>>(x, xb);
    qlin_gemm<<<NBLK, 256, 0, stream>>>(xb, wp, sc, bias, out);
}

// Round 4
// 358.200 us; speedup vs baseline: 1.1876x; 1.1395x over previous
//
#include <hip/hip_runtime.h>

#define IN_F   8192
#define OUT_F  14336
#define M_TOK  64
#define KPI    4096              // packed int32 per weight row
#define BN     128               // n per block (4 waves x 32)
#define NBLK   (OUT_F / BN)      // 112
#define KSPLIT 8
#define KCHUNK (IN_F / KSPLIT)   // 1024 k per block
#define BK     128               // k per staging step
#define NSTEP  (KCHUNK / BK)     // 8

typedef __attribute__((ext_vector_type(8)))  short bf16x8;   // 8 bf16 (4 VGPRs)
typedef __attribute__((ext_vector_type(16))) float f32x16;   // 32x32 MFMA C/D frag

__device__ __forceinline__ unsigned short f2bf_rne(float f) {
    unsigned u = __builtin_bit_cast(unsigned, f);
    u += 0x7FFFu + ((u >> 16) & 1u);
    return (unsigned short)(u >> 16);
}

// Prep: x fp32 -> bf16 workspace; out[m][n] = bias[n] (gemm atomically accumulates).
__global__ __launch_bounds__(256) void qlin_prep(const float* __restrict__ x,
                                                 const float* __restrict__ bias,
                                                 unsigned short* __restrict__ xb,
                                                 float* __restrict__ out) {
    const int XV = (M_TOK * IN_F) / 4;    // 131072
    const int OV = (M_TOK * OUT_F) / 4;   // 229376
    int gid = blockIdx.x * 256 + threadIdx.x;
    if (gid < XV) {
        float4 v = reinterpret_cast<const float4*>(x)[gid];
        ushort4 o;
        o.x = f2bf_rne(v.x);
        o.y = f2bf_rne(v.y);
        o.z = f2bf_rne(v.z);
        o.w = f2bf_rne(v.w);
        reinterpret_cast<ushort4*>(xb)[gid] = o;
    } else {
        int og = gid - XV;
        if (og < OV) {
            float4 b = reinterpret_cast<const float4*>(bias)[og % (OUT_F / 4)];
            reinterpret_cast<float4*>(out)[og] = b;
        }
    }
}

// One packed int32 (byte: lo nibble = even k, hi nibble = odd k) -> two bf16
// bit-patterns in one dword. Ints in [-8,7] are exact in bf16.
__device__ __forceinline__ int unpack2_bf16(int v) {
    int q0 = ((int)((unsigned)v << 28)) >> 28;
    int q1 = ((int)((unsigned)v << 24)) >> 28;
    unsigned u0 = __builtin_bit_cast(unsigned, (float)q0);
    unsigned u1 = __builtin_bit_cast(unsigned, (float)q1);
    return (int)((u0 >> 16) | (u1 & 0xFFFF0000u));
}

__device__ __forceinline__ bf16x8 unpack_b(int4 wv) {
    int4 pk;
    pk.x = unpack2_bf16(wv.x);
    pk.y = unpack2_bf16(wv.y);
    pk.z = unpack2_bf16(wv.z);
    pk.w = unpack2_bf16(wv.w);
    return __builtin_bit_cast(bf16x8, pk);
}

// async 16-B global -> LDS (dest = wave-uniform base + lane*16; our lds offsets
// are exactly instr_base + lane*16, so the layout contract holds).
__device__ __forceinline__ void gload_lds16(const void* g, void* l) {
    __builtin_amdgcn_global_load_lds(
        (const __attribute__((address_space(1))) unsigned int*)g,
        (__attribute__((address_space(3))) unsigned int*)l,
        16, 0, 0);
}

// Block: 128 n x 64 m, k-chunk 1024 in 8 steps of BK=128.
// Per step: coalesced global_load_lds of w-tile (packed, 32 KB) + x-tile (16 KB);
// barrier; each wave (own 32 n) does 8 b-frags + 16 a-frags + 16 mfma_32x32x16.
// Epilogue: scale + atomicAdd into bias-initialized out (KSPLIT partials).
__global__ __launch_bounds__(256) void qlin_gemm(const unsigned short* __restrict__ xb,
                                                 const int* __restrict__ wp,
                                                 const float* __restrict__ scales,
                                                 float* __restrict__ out) {
    __shared__ int            wlds[BN * (BK / 2)];   // [128 rows][64 int32] = 32 KB
    __shared__ unsigned short xlds[M_TOK * BK];      // [64 rows][128 bf16]  = 16 KB

    const int tid  = threadIdx.x;
    const int wave = tid >> 6;
    const int lane = tid & 63;
    const int tp   = lane & 31;   // 32x32 frag: n (B) / m (A) / col (C)
    const int qp   = lane >> 5;   // 32x32 frag: k half ; C/D row offset 4*qp

    const int nblk = blockIdx.x % NBLK;
    const int kblk = blockIdx.x / NBLK;
    const int n0   = nblk * BN;
    const int kb   = kblk * KCHUNK;        // k base (elements)

    f32x16 acc0 = {0.f,0.f,0.f,0.f,0.f,0.f,0.f,0.f,0.f,0.f,0.f,0.f,0.f,0.f,0.f,0.f};
    f32x16 acc1 = acc0;

    for (int step = 0; step < NSTEP; ++step) {
        // ---- stage w-tile: 32 instrs of 1 KB; wave w does 8 ----
#pragma unroll
        for (int j = 0; j < 8; ++j) {
            int li = (wave * 8 + j) * 64 + lane;   // 16-B chunk index 0..2047
            int r  = li >> 4;                      // weight row 0..127
            int c  = li & 15;                      // 16-B chunk within row slice
            const int* gp = wp + (size_t)(n0 + r) * KPI + (kb >> 1) + step * (BK / 2) + c * 4;
            gload_lds16(gp, (char*)wlds + (size_t)li * 16);
        }
        // ---- stage x-tile: 16 instrs of 1 KB; wave w does 4 ----
#pragma unroll
        for (int j = 0; j < 4; ++j) {
            int li = (wave * 4 + j) * 64 + lane;   // 16-B chunk index 0..1023
            int r  = li >> 4;                      // m row 0..63
            int c  = li & 15;
            const unsigned short* gp = xb + (size_t)r * IN_F + kb + step * BK + c * 8;
            gload_lds16(gp, (char*)xlds + (size_t)li * 16);
        }
        __syncthreads();   // drains vmcnt before any ds_read

        // ---- compute: wave owns n = n0 + wave*32 + tp ----
#pragma unroll
        for (int kf = 0; kf < 8; ++kf) {
            int4 wv = *reinterpret_cast<const int4*>(
                (const char*)wlds + ((wave * 32 + tp) * (BK / 2) + kf * 8 + qp * 4) * 4);
            bf16x8 b  = unpack_b(wv);
            bf16x8 a0 = *reinterpret_cast<const bf16x8*>(
                (const char*)xlds + ((tp)      * BK + kf * 16 + qp * 8) * 2);
            bf16x8 a1 = *reinterpret_cast<const bf16x8*>(
                (const char*)xlds + ((32 + tp) * BK + kf * 16 + qp * 8) * 2);
            acc0 = __builtin_amdgcn_mfma_f32_32x32x16_bf16(a0, b, acc0, 0, 0, 0);
            acc1 = __builtin_amdgcn_mfma_f32_32x32x16_bf16(a1, b, acc1, 0, 0, 0);
        }
        __syncthreads();   // tile consumed; safe to overwrite next step
    }

    // ---- epilogue: C/D 32x32 layout col=tp, row=(reg&3)+8*(reg>>2)+4*qp ----
    const int   n  = n0 + wave * 32 + tp;
    const float sc = scales[n];
#pragma unroll
    for (int reg = 0; reg < 16; ++reg) {
        int m = (reg & 3) + 8 * (reg >> 2) + 4 * qp;
        atomicAdd(&out[(size_t)m        * OUT_F + n], acc0[reg] * sc);
        atomicAdd(&out[(size_t)(32 + m) * OUT_F + n], acc1[reg] * sc);
    }
}

extern "C" void kernel_launch(void* const* d_in, const int* in_sizes, int n_in,
                              void* d_out, int out_size, void* d_ws, size_t ws_size,
                              hipStream_t stream) {
    const float* x    = (const float*)d_in[0];
    const int*   wp   = (const int*)d_in[1];
    const float* sc   = (const float*)d_in[2];
    const float* bias = (const float*)d_in[3];
    float* out = (float*)d_out;
    unsigned short* xb = (unsigned short*)d_ws;   // 64*8192*2 = 1 MB

    const int prep_items = (M_TOK * IN_F) / 4 + (M_TOK * OUT_F) / 4;  // 360448
    qlin_prep<<<(prep_items + 255) / 256, 256, 0, stream>>>(x, bias, xb, out);
    qlin_gemm<<<NBLK * KSPLIT, 256, 0, stream>>>(xb, wp, sc, out);
}

// Round 5
// 355.875 us; speedup vs baseline: 1.1953x; 1.0065x over previous
//
#include <hip/hip_runtime.h>

#define IN_F   8192
#define OUT_F  14336
#define M_TOK  64
#define KPI    4096              // packed int32 per weight row
#define BN     128               // n per block (4 waves x 32)
#define NBLK   (OUT_F / BN)      // 112
#define KSPLIT 16
#define KCHUNK (IN_F / KSPLIT)   // 512 k per block
#define BK     64                // k per staging step
#define NSTEP  (KCHUNK / BK)     // 8
#define PSTRIDE (M_TOK * OUT_F)  // floats per k-split partial = 917504

typedef __attribute__((ext_vector_type(8)))  short bf16x8;   // 8 bf16 (4 VGPRs)
typedef __attribute__((ext_vector_type(16))) float f32x16;   // 32x32 MFMA C/D frag

__device__ __forceinline__ unsigned short f2bf_rne(float f) {
    unsigned u = __builtin_bit_cast(unsigned, f);
    u += 0x7FFFu + ((u >> 16) & 1u);
    return (unsigned short)(u >> 16);
}

// Prep: x fp32 -> bf16 workspace (out is fully written by qlin_reduce).
__global__ __launch_bounds__(256) void qlin_prep(const float* __restrict__ x,
                                                 unsigned short* __restrict__ xb) {
    int gid = blockIdx.x * 256 + threadIdx.x;   // 131072 float4
    float4 v = reinterpret_cast<const float4*>(x)[gid];
    ushort4 o;
    o.x = f2bf_rne(v.x);
    o.y = f2bf_rne(v.y);
    o.z = f2bf_rne(v.z);
    o.w = f2bf_rne(v.w);
    reinterpret_cast<ushort4*>(xb)[gid] = o;
}

// One packed int32 (byte: lo nibble = even k, hi nibble = odd k) -> two bf16
// bit-patterns in one dword. Ints in [-8,7] are exact in bf16.
__device__ __forceinline__ int unpack2_bf16(int v) {
    int q0 = ((int)((unsigned)v << 28)) >> 28;
    int q1 = ((int)((unsigned)v << 24)) >> 28;
    unsigned u0 = __builtin_bit_cast(unsigned, (float)q0);
    unsigned u1 = __builtin_bit_cast(unsigned, (float)q1);
    return (int)((u0 >> 16) | (u1 & 0xFFFF0000u));
}

__device__ __forceinline__ bf16x8 unpack_b(int4 wv) {
    int4 pk;
    pk.x = unpack2_bf16(wv.x);
    pk.y = unpack2_bf16(wv.y);
    pk.z = unpack2_bf16(wv.z);
    pk.w = unpack2_bf16(wv.w);
    return __builtin_bit_cast(bf16x8, pk);
}

// async 16-B global -> LDS (LDS dest = wave-uniform base + lane*16, fixed by HW).
__device__ __forceinline__ void gload_lds16(const void* g, void* l) {
    __builtin_amdgcn_global_load_lds(
        (const __attribute__((address_space(1))) unsigned int*)g,
        (__attribute__((address_space(3))) unsigned int*)l,
        16, 0, 0);
}

// Block: 128 n x 64 m, k-chunk 512 in 8 steps of BK=64. LDS 24 KB -> 6 blocks/CU
// (the round-4 convoy fix: more independent staging phases per CU).
// Bank-conflict fix within the load_lds contract: swizzle on the GLOBAL side —
// LDS slot (row r, chunk cl) holds global 16-B chunk cl^(r&7); readers index
// slot r*8 + (c^(r&7)) so 8 lanes/cycle cover all 32 banks (conflict-free b128).
// Epilogue: plain stores of scale-applied partials into ws (no atomics).
__global__ __launch_bounds__(256, 6) void qlin_gemm(const unsigned short* __restrict__ xb,
                                                    const int* __restrict__ wp,
                                                    const float* __restrict__ scales,
                                                    float* __restrict__ part) {
    __shared__ int            wlds[BN * (BK / 2)];     // 128 rows x 32 int32 = 16 KB
    __shared__ unsigned short xlds[M_TOK * BK];        // 64 rows x 64 bf16   =  8 KB

    const int tid  = threadIdx.x;
    const int wave = tid >> 6;
    const int lane = tid & 63;
    const int tp   = lane & 31;   // 32x32 frag: n (B) / m (A) / col (C)
    const int qp   = lane >> 5;   // 32x32 frag: k-half ; C/D row offset 4*qp

    const int nblk = blockIdx.x % NBLK;
    const int kblk = blockIdx.x / NBLK;
    const int n0   = nblk * BN;
    const int kb   = kblk * KCHUNK;        // k base (elements)

    f32x16 acc0 = {0.f,0.f,0.f,0.f,0.f,0.f,0.f,0.f,0.f,0.f,0.f,0.f,0.f,0.f,0.f,0.f};
    f32x16 acc1 = acc0;

    for (int step = 0; step < NSTEP; ++step) {
        // ---- stage w-tile: 16 KB = 16 instrs, 4/wave ----
#pragma unroll
        for (int j = 0; j < 4; ++j) {
            int li = (wave * 4 + j) * 64 + lane;       // slot 0..1023
            int r  = li >> 3;                          // weight row 0..127
            int cg = (li & 7) ^ (r & 7);               // global chunk (swizzled)
            const int* gp = wp + (size_t)(n0 + r) * KPI + (kb >> 1) + step * (BK / 2) + cg * 4;
            gload_lds16(gp, (char*)wlds + (size_t)li * 16);
        }
        // ---- stage x-tile: 8 KB = 8 instrs, 2/wave ----
#pragma unroll
        for (int j = 0; j < 2; ++j) {
            int li = (wave * 2 + j) * 64 + lane;       // slot 0..511
            int r  = li >> 3;                          // m row 0..63
            int cg = (li & 7) ^ (r & 7);
            const unsigned short* gp = xb + (size_t)r * IN_F + kb + step * BK + cg * 8;
            gload_lds16(gp, (char*)xlds + (size_t)li * 16);
        }
        __syncthreads();

        // ---- compute: wave owns n-rows wave*32 + tp ----
#pragma unroll
        for (int kf = 0; kf < 4; ++kf) {
            const int c = kf * 2 + qp;                 // 16-B chunk within row
            const int R = wave * 32 + tp;
            int4 wv = *reinterpret_cast<const int4*>(
                (const char*)wlds + (size_t)(R * 8 + (c ^ (R & 7))) * 16);
            bf16x8 b  = unpack_b(wv);
            bf16x8 a0 = *reinterpret_cast<const bf16x8*>(
                (const char*)xlds + (size_t)(tp * 8 + (c ^ (tp & 7))) * 16);
            bf16x8 a1 = *reinterpret_cast<const bf16x8*>(
                (const char*)xlds + (size_t)((32 + tp) * 8 + (c ^ (tp & 7))) * 16);
            acc0 = __builtin_amdgcn_mfma_f32_32x32x16_bf16(a0, b, acc0, 0, 0, 0);
            acc1 = __builtin_amdgcn_mfma_f32_32x32x16_bf16(a1, b, acc1, 0, 0, 0);
        }
        __syncthreads();
    }

    // ---- epilogue: C/D layout col=tp, row=(reg&3)+8*(reg>>2)+4*qp; plain stores ----
    const int   n  = n0 + wave * 32 + tp;
    const float sc = scales[n];
    float* p = part + (size_t)kblk * PSTRIDE;
#pragma unroll
    for (int reg = 0; reg < 16; ++reg) {
        int m = (reg & 3) + 8 * (reg >> 2) + 4 * qp;
        p[(size_t)m        * OUT_F + n] = acc0[reg] * sc;
        p[(size_t)(32 + m) * OUT_F + n] = acc1[reg] * sc;
    }
}

// out[m][n] = bias[n] + sum over 16 k-split partials. 229376 float4 threads.
__global__ __launch_bounds__(256) void qlin_reduce(const float* __restrict__ part,
                                                   const float* __restrict__ bias,
                                                   float* __restrict__ out) {
    int g = blockIdx.x * 256 + threadIdx.x;            // 0..229375
    float4 acc = reinterpret_cast<const float4*>(bias)[g % (OUT_F / 4)];
#pragma unroll
    for (int s = 0; s < KSPLIT; ++s) {
        float4 v = reinterpret_cast<const float4*>(part + (size_t)s * PSTRIDE)[g];
        acc.x += v.x; acc.y += v.y; acc.z += v.z; acc.w += v.w;
    }
    reinterpret_cast<float4*>(out)[g] = acc;
}

extern "C" void kernel_launch(void* const* d_in, const int* in_sizes, int n_in,
                              void* d_out, int out_size, void* d_ws, size_t ws_size,
                              hipStream_t stream) {
    const float* x    = (const float*)d_in[0];
    const int*   wp   = (const int*)d_in[1];
    const float* sc   = (const float*)d_in[2];
    const float* bias = (const float*)d_in[3];
    float* out = (float*)d_out;

    unsigned short* xb   = (unsigned short*)d_ws;                   // 1 MB
    float*          part = (float*)((char*)d_ws + (1 << 20));       // 16 x 3.67 MB

    qlin_prep<<<(M_TOK * IN_F) / 4 / 256, 256, 0, stream>>>(x, xb);
    qlin_gemm<<<NBLK * KSPLIT, 256, 0, stream>>>(xb, wp, sc, part);
    qlin_reduce<<<(M_TOK * OUT_F) / 4 / 256, 256, 0, stream>>>(part, bias, out);
}